// Round 19
// baseline (560.795 us; speedup 1.0000x reference)
//
#include <hip/hip_runtime.h>
#include <float.h>

// Sparsemax attention v11: 32 rows/wave (K loads amortized 2x) + fused
// collect-in-pass-2 (common path = 2 scans).  B=2,H=16,S=2048,D=64 fp32, T=8.
//
// r18 post-mortem: scans are L2-BW-bound (each wave reads 256KB of K per
// scan; 3 scans x 4096 waves = 3 GB ~ 90us). Fix:
//   - wave owns TWO 16-row MFMA tiles; every K fragment pair feeds 4 MFMAs
//     -> 2048 waves, traffic/scan halved.
//   - pass 2: capless (sum,count)@(max-8) -> t1  AND  capped collect@(max-8)
//     (LCAP=20/lane). No overflow (most waves) -> Michelot on lists from t1,
//     NO pass 3. Overflow -> pass 3 recollect@t1 (+(s,c)@t1 -> t2); still
//     overflow -> full-scan Michelot from t2 + dense PV (rare, correct).
//   - after tau: lanes rewrite own slots as packed p|col (tau folded in);
//     PV per row-tile sequentially (oac[16] reused), branchless, sentinel-
//     padded. Zero barriers; waves fully independent.

#define S_LEN 2048
#define DHEAD 64
#define BWAVES 4
#define LCAP 20

typedef _Float16 f16x8 __attribute__((ext_vector_type(8)));
typedef __attribute__((ext_vector_type(4))) float f32x4;

__device__ __forceinline__ unsigned short f2h(float x) {
    return __builtin_bit_cast(unsigned short, (_Float16)x);
}
__device__ __forceinline__ unsigned int pk2h(float lo, float hi) {
    return (unsigned int)f2h(lo) | ((unsigned int)f2h(hi) << 16);
}
__device__ __forceinline__ f16x8 cvt8h(float4 a, float4 b) {
    union { unsigned int u[4]; f16x8 v; } r;
    r.u[0] = pk2h(a.x, a.y); r.u[1] = pk2h(a.z, a.w);
    r.u[2] = pk2h(b.x, b.y); r.u[3] = pk2h(b.z, b.w);
    return r.v;
}

// K fp32 [bh][2048][64] -> fragment-contiguous fp16 (r14-proven layout).
__global__ __launch_bounds__(256)
void kswz_kernel(const float* __restrict__ K, uint4* __restrict__ dst, int nfrag) {
    int tid = blockIdx.x * 256 + threadIdx.x;
    if (tid >= nfrag) return;
    const int lane = tid & 63;
    const int grp  = (tid >> 6) & 1;
    const int ct   = (tid >> 7) & 127;
    const int bh   = tid >> 14;
    const int row  = ct * 16 + (lane & 15);
    const int col  = grp * 32 + (lane >> 4) * 8;
    const float* src = K + ((size_t)bh * S_LEN + row) * DHEAD + col;
    float4 a = *reinterpret_cast<const float4*>(src);
    float4 b = *reinterpret_cast<const float4*>(src + 4);
    uint4 o;
    o.x = pk2h(a.x, a.y); o.y = pk2h(a.z, a.w);
    o.z = pk2h(b.x, b.y); o.w = pk2h(b.z, b.w);
    dst[tid] = o;
}

__global__ __launch_bounds__(256, 4)
void spx_main(const float* __restrict__ Q,
              const unsigned short* __restrict__ Ks,
              const float* __restrict__ V,
              float* __restrict__ O)
{
    // [wave][rowtile][slot][lane] = 40 KB; wave chunk (10 KB) doubles as
    // the dense-fallback p-buffer (8 KB needed).
    __shared__ unsigned int s_pack[BWAVES][2][LCAP][64];

    const int t    = threadIdx.x;
    const int widx = t >> 6;
    const int l    = t & 63;
    const int lm   = l & 15;
    const int lk   = l >> 4;

    int bid = blockIdx.x;
    if (((int)gridDim.x & 7) == 0)
        bid = (bid & 7) * ((int)gridDim.x >> 3) + (bid >> 3);   // XCD swizzle
    const int nrb   = S_LEN / (32 * BWAVES);         // 16 row-blocks per bh
    const int bh    = bid / nrb;
    const int row0w = (bid % nrb) * (32 * BWAVES) + widx * 32;

    const float* Qf = Q + (size_t)bh * S_LEN * DHEAD;
    const unsigned short* KsB = Ks + (size_t)bh * S_LEN * DHEAD;
    const float* Vb = V + (size_t)bh * S_LEN * DHEAD;
    float* Of = O + (size_t)bh * S_LEN * DHEAD;

    // ---- Q^T B-fragments, two 16-row tiles ----
    f16x8 qfrag[2][2];
    #pragma unroll
    for (int rt = 0; rt < 2; ++rt)
        #pragma unroll
        for (int kp = 0; kp < 2; ++kp) {
            const float* qp = Qf + (size_t)(row0w + rt * 16 + lm) * DHEAD
                                 + kp * 32 + lk * 8;
            qfrag[rt][kp] = cvt8h(*reinterpret_cast<const float4*>(qp),
                                  *reinterpret_cast<const float4*>(qp + 4));
        }

    // both row-tiles from ONE K fragment pair (4 MFMA / 2 loads)
    #define SCORE_TILE2(a0_, a1_, ct_)                                           \
        {                                                                        \
            const unsigned short* kb_ = KsB + (size_t)(ct_) * 1024;              \
            f16x8 k0_ = *reinterpret_cast<const f16x8*>(kb_ + l * 8);            \
            f16x8 k1_ = *reinterpret_cast<const f16x8*>(kb_ + 512 + l * 8);      \
            a0_ = (f32x4){0.f, 0.f, 0.f, 0.f};                                   \
            a1_ = (f32x4){0.f, 0.f, 0.f, 0.f};                                   \
            a0_ = __builtin_amdgcn_mfma_f32_16x16x32_f16(k0_, qfrag[0][0], a0_, 0, 0, 0); \
            a0_ = __builtin_amdgcn_mfma_f32_16x16x32_f16(k1_, qfrag[0][1], a0_, 0, 0, 0); \
            a1_ = __builtin_amdgcn_mfma_f32_16x16x32_f16(k0_, qfrag[1][0], a1_, 0, 0, 0); \
            a1_ = __builtin_amdgcn_mfma_f32_16x16x32_f16(k1_, qfrag[1][1], a1_, 0, 0, 0); \
        }

    // single row-tile (fallback paths), rt_ must be compile-time
    #define SCORE_TILE1(a_, rt_, ct_)                                            \
        {                                                                        \
            const unsigned short* kb_ = KsB + (size_t)(ct_) * 1024;              \
            f16x8 k0_ = *reinterpret_cast<const f16x8*>(kb_ + l * 8);            \
            f16x8 k1_ = *reinterpret_cast<const f16x8*>(kb_ + 512 + l * 8);      \
            a_ = (f32x4){0.f, 0.f, 0.f, 0.f};                                    \
            a_ = __builtin_amdgcn_mfma_f32_16x16x32_f16(k0_, qfrag[rt_][0], a_, 0, 0, 0); \
            a_ = __builtin_amdgcn_mfma_f32_16x16x32_f16(k1_, qfrag[rt_][1], a_, 0, 0, 0); \
        }

    // ---- pass 1: row max for both row-tiles ----
    float mx0 = -FLT_MAX, mx1 = -FLT_MAX;
    #pragma unroll 4
    for (int ct = 0; ct < S_LEN / 16; ++ct) {
        f32x4 a0, a1;
        SCORE_TILE2(a0, a1, ct);
        mx0 = fmaxf(mx0, fmaxf(fmaxf(a0[0], a0[1]), fmaxf(a0[2], a0[3])));
        mx1 = fmaxf(mx1, fmaxf(fmaxf(a1[0], a1[1]), fmaxf(a1[2], a1[3])));
    }
    mx0 = fmaxf(mx0, __shfl_xor(mx0, 16)); mx0 = fmaxf(mx0, __shfl_xor(mx0, 32));
    mx1 = fmaxf(mx1, __shfl_xor(mx1, 16)); mx1 = fmaxf(mx1, __shfl_xor(mx1, 32));

    // ---- pass 2: capless (sum,count)@(max-8) -> t1, plus capped collect ----
    const float thr0 = mx0 - 8.f, thr1 = mx1 - 8.f;
    int own0 = 0, own1 = 0;
    float ls0 = 0.f, ls1 = 0.f;
    #pragma unroll 2
    for (int ct = 0; ct < S_LEN / 16; ++ct) {
        f32x4 a0, a1;
        SCORE_TILE2(a0, a1, ct);
        #pragma unroll
        for (int e = 0; e < 4; ++e) {
            const float v0 = a0[e];
            if (v0 > thr0) {
                ls0 += v0;
                if (own0 < LCAP)
                    s_pack[widx][0][own0][l] =
                        (__builtin_bit_cast(unsigned int, v0) & 0xFFFFF800u)
                        | (unsigned int)(ct * 16 + lk * 4 + e);
                ++own0;
            }
            const float v1 = a1[e];
            if (v1 > thr1) {
                ls1 += v1;
                if (own1 < LCAP)
                    s_pack[widx][1][own1][l] =
                        (__builtin_bit_cast(unsigned int, v1) & 0xFFFFF800u)
                        | (unsigned int)(ct * 16 + lk * 4 + e);
                ++own1;
            }
        }
    }
    for (int i = (own0 < LCAP ? own0 : LCAP); i < LCAP; ++i)
        s_pack[widx][0][i][l] = 0xFF800000u;
    for (int i = (own1 < LCAP ? own1 : LCAP); i < LCAP; ++i)
        s_pack[widx][1][i][l] = 0xFF800000u;

    float s0 = ls0, s1 = ls1;
    float c0 = (float)own0, c1 = (float)own1;
    s0 += __shfl_xor(s0, 16); c0 += __shfl_xor(c0, 16);
    s0 += __shfl_xor(s0, 32); c0 += __shfl_xor(c0, 32);
    s1 += __shfl_xor(s1, 16); c1 += __shfl_xor(c1, 16);
    s1 += __shfl_xor(s1, 32); c1 += __shfl_xor(c1, 32);
    float start0 = (s0 - 8.f) / c0;                   // t1, exact
    float start1 = (s1 - 8.f) / c1;

    bool ovf = __any((own0 > LCAP) || (own1 > LCAP));
    if (ovf) {
        // ---- pass 3 (minority of waves): recollect @ t1, (s,c)@t1 -> t2 ----
        own0 = 0; own1 = 0; ls0 = 0.f; ls1 = 0.f;
        const float th0 = start0, th1 = start1;
        #pragma unroll 2
        for (int ct = 0; ct < S_LEN / 16; ++ct) {
            f32x4 a0, a1;
            SCORE_TILE2(a0, a1, ct);
            #pragma unroll
            for (int e = 0; e < 4; ++e) {
                const float v0 = a0[e];
                if (v0 > th0) {
                    ls0 += v0;
                    if (own0 < LCAP)
                        s_pack[widx][0][own0][l] =
                            (__builtin_bit_cast(unsigned int, v0) & 0xFFFFF800u)
                            | (unsigned int)(ct * 16 + lk * 4 + e);
                    ++own0;
                }
                const float v1 = a1[e];
                if (v1 > th1) {
                    ls1 += v1;
                    if (own1 < LCAP)
                        s_pack[widx][1][own1][l] =
                            (__builtin_bit_cast(unsigned int, v1) & 0xFFFFF800u)
                            | (unsigned int)(ct * 16 + lk * 4 + e);
                    ++own1;
                }
            }
        }
        for (int i = (own0 < LCAP ? own0 : LCAP); i < LCAP; ++i)
            s_pack[widx][0][i][l] = 0xFF800000u;
        for (int i = (own1 < LCAP ? own1 : LCAP); i < LCAP; ++i)
            s_pack[widx][1][i][l] = 0xFF800000u;
        float s0b = ls0, s1b = ls1, c0b = (float)own0, c1b = (float)own1;
        s0b += __shfl_xor(s0b, 16); c0b += __shfl_xor(c0b, 16);
        s0b += __shfl_xor(s0b, 32); c0b += __shfl_xor(c0b, 32);
        s1b += __shfl_xor(s1b, 16); c1b += __shfl_xor(c1b, 16);
        s1b += __shfl_xor(s1b, 32); c1b += __shfl_xor(c1b, 32);
        start0 = (s0b - 8.f) / c0b;                   // t2, exact
        start1 = (s1b - 8.f) / c1b;
        ovf = __any((own0 > LCAP) || (own1 > LCAP));
    }

    if (!ovf) {
        // ---- per row-tile: list Michelot -> tau, rewrite p|col, sparse PV ----
        #pragma unroll
        for (int rt = 0; rt < 2; ++rt) {
            const int ownr = rt ? own1 : own0;
            float tv = rt ? start1 : start0;
            {
                float cand[LCAP];
                #pragma unroll
                for (int s = 0; s < LCAP; ++s)
                    cand[s] = __builtin_bit_cast(
                        float, s_pack[widx][rt][s][l] & 0xFFFFF800u);
                int cprev = -1;
                for (int it = 0; it < 20; ++it) {
                    float ss = 0.f, cc = 0.f;
                    #pragma unroll
                    for (int q = 0; q < LCAP; ++q) {
                        const bool in = cand[q] > tv;
                        ss += in ? cand[q] : 0.f;
                        cc += in ? 1.f : 0.f;
                    }
                    ss += __shfl_xor(ss, 16); cc += __shfl_xor(cc, 16);
                    ss += __shfl_xor(ss, 32); cc += __shfl_xor(cc, 32);
                    tv = (ss - 8.f) / cc;
                    const int C = (int)cc;
                    const bool done = (C == cprev);
                    cprev = C;
                    if (__all(done ? 1 : 0)) break;   // fixpoint: exact tau
                }
            }
            // rewrite own slots: p = max(val - tau, 0) packed with col
            #pragma unroll
            for (int s = 0; s < LCAP; ++s) {
                const unsigned int pk = s_pack[widx][rt][s][l];
                const float val = __builtin_bit_cast(float, pk & 0xFFFFF800u);
                const float p = fmaxf(val - tv, 0.f);
                s_pack[widx][rt][s][l] =
                    (__builtin_bit_cast(unsigned int, p) & 0xFFFFF800u)
                    | (pk & 0x7FFu);
            }
            // wave-max slot count for this row-tile
            int mc = ownr < LCAP ? ownr : LCAP;
            #pragma unroll
            for (int o = 1; o < 64; o <<= 1) {
                const int m2 = __shfl_xor(mc, o);
                mc = m2 > mc ? m2 : mc;
            }
            // branchless interleaved sparse PV (64 indep chains per slot)
            float oac[16];
            #pragma unroll
            for (int r = 0; r < 16; ++r) oac[r] = 0.f;
            const float* Vl = Vb + l;
            for (int i = 0; i < mc; ++i) {
                #pragma unroll
                for (int r = 0; r < 16; ++r) {
                    #pragma unroll
                    for (int j = 0; j < 4; ++j) {
                        const unsigned int pk = s_pack[widx][rt][i][r + 16 * j];
                        const float p =
                            __builtin_bit_cast(float, pk & 0xFFFFF800u);
                        const int col = (int)(pk & 0x7FFu);
                        oac[r] = fmaf(p, Vl[(size_t)col * DHEAD], oac[r]);
                    }
                }
            }
            #pragma unroll
            for (int r = 0; r < 16; ++r)
                Of[(size_t)(row0w + rt * 16 + r) * DHEAD + l] = oac[r] * 0.125f;
        }
    } else {
        // ---- fallback (rare, any-data-correct): full-scan Michelot from t2 ----
        float tv0 = start0, tv1 = start1;
        int c0p = -1, c1p = -1;
        for (int it = 0; it < 12; ++it) {
            float sa = 0.f, ca = 0.f, sb = 0.f, cb = 0.f;
            #pragma unroll 2
            for (int ct = 0; ct < S_LEN / 16; ++ct) {
                f32x4 a0, a1;
                SCORE_TILE2(a0, a1, ct);
                #pragma unroll
                for (int e = 0; e < 4; ++e) {
                    const bool i0 = a0[e] > tv0;
                    sa += i0 ? a0[e] : 0.f;  ca += i0 ? 1.f : 0.f;
                    const bool i1 = a1[e] > tv1;
                    sb += i1 ? a1[e] : 0.f;  cb += i1 ? 1.f : 0.f;
                }
            }
            sa += __shfl_xor(sa, 16); ca += __shfl_xor(ca, 16);
            sa += __shfl_xor(sa, 32); ca += __shfl_xor(ca, 32);
            sb += __shfl_xor(sb, 16); cb += __shfl_xor(cb, 16);
            sb += __shfl_xor(sb, 32); cb += __shfl_xor(cb, 32);
            tv0 = (sa - 8.f) / ca;
            tv1 = (sb - 8.f) / cb;
            const int C0 = (int)ca, C1 = (int)cb;
            const bool done = (C0 == c0p) && (C1 == c1p);
            c0p = C0; c1p = C1;
            if (__all(done ? 1 : 0)) break;
        }
        // dense chunked PV per row-tile via wave's own 10 KB LDS chunk
        float* p_lds = reinterpret_cast<float*>(&s_pack[widx][0][0][0]);
        #pragma unroll
        for (int rt = 0; rt < 2; ++rt) {
            const float tvr = rt ? tv1 : tv0;
            float ofb[16];
            #pragma unroll
            for (int r = 0; r < 16; ++r) ofb[r] = 0.f;
            for (int cc = 0; cc < 16; ++cc) {
                #pragma unroll
                for (int tt = 0; tt < 8; ++tt) {
                    f32x4 a;
                    SCORE_TILE1(a, rt, cc * 8 + tt);
                    #pragma unroll
                    for (int e = 0; e < 4; ++e)
                        p_lds[lm * 128 + tt * 16 + lk * 4 + e] =
                            fmaxf(a[e] - tvr, 0.f);
                }
                for (int c2 = 0; c2 < 128; ++c2) {
                    const float vv = Vb[(size_t)(cc * 128 + c2) * DHEAD + l];
                    #pragma unroll
                    for (int r = 0; r < 16; ++r)
                        ofb[r] += p_lds[r * 128 + c2] * vv;
                }
            }
            #pragma unroll
            for (int r = 0; r < 16; ++r)
                Of[(size_t)(row0w + rt * 16 + r) * DHEAD + l] = ofb[r] * 0.125f;
        }
    }
    #undef SCORE_TILE2
    #undef SCORE_TILE1
}

extern "C" void kernel_launch(void* const* d_in, const int* in_sizes, int n_in,
                              void* d_out, int out_size, void* d_ws, size_t ws_size,
                              hipStream_t stream) {
    const float* q = (const float*)d_in[0];
    const float* k = (const float*)d_in[1];
    const float* v = (const float*)d_in[2];
    float* out = (float*)d_out;

    const int nElem = in_sizes[0];                    // B*H*S*D = 4194304
    const int BH    = nElem / (S_LEN * DHEAD);

    unsigned short* ks = (unsigned short*)d_ws;
    const int nfrag = nElem / 8;
    kswz_kernel<<<(nfrag + 255) / 256, 256, 0, stream>>>(k, (uint4*)ks, nfrag);

    const int grid = BH * (S_LEN / (32 * BWAVES));    // 512 blocks
    spx_main<<<grid, 256, 0, stream>>>(q, ks, v, out);
}

// Round 20
// 181.137 us; speedup vs baseline: 3.0960x; 3.0960x over previous
//
#include <hip/hip_runtime.h>
#include <float.h>

// Sparsemax attention v12 = r18 + fused collect-in-pass-2 (skip pass 3 when
// the lane cap holds).  B=2,H=16,S=2048,D=64 fp32, temperature 8.
//
// r19 post-mortem: 32-rows/wave doubled live registers -> in-loop scratch
// spill (WRITE 305MB). Reverted. This round keeps r18's proven register
// profile (16 rows/wave, 64 VGPR, zero spill) and makes ONE change:
//   pass 2: capless (sum,count)@(max-8) -> t1  AND capped collect@(max-8)
//           (LCAP=32/lane, same fused loop shape as r18's pass 3).
//   no overflow (most waves): Michelot on the list from t1 -- pass 3 SKIPPED
//   -> common path is 2 K-scans instead of 3 (scans are the L2-BW wall).
//   overflow: r18's pass 3 (recollect@t1 -> t2); still-overflow: r18's
//   full-scan Michelot from t2 + dense chunked PV (any-data correct).

#define S_LEN 2048
#define DHEAD 64
#define WROWS 16
#define BWAVES 4
#define LCAP 32

typedef _Float16 f16x8 __attribute__((ext_vector_type(8)));
typedef __attribute__((ext_vector_type(4))) float f32x4;

__device__ __forceinline__ unsigned short f2h(float x) {
    return __builtin_bit_cast(unsigned short, (_Float16)x);
}
__device__ __forceinline__ unsigned int pk2h(float lo, float hi) {
    return (unsigned int)f2h(lo) | ((unsigned int)f2h(hi) << 16);
}
__device__ __forceinline__ f16x8 cvt8h(float4 a, float4 b) {
    union { unsigned int u[4]; f16x8 v; } r;
    r.u[0] = pk2h(a.x, a.y); r.u[1] = pk2h(a.z, a.w);
    r.u[2] = pk2h(b.x, b.y); r.u[3] = pk2h(b.z, b.w);
    return r.v;
}

// K fp32 [bh][2048][64] -> fragment-contiguous fp16 (r14-proven layout).
__global__ __launch_bounds__(256)
void kswz_kernel(const float* __restrict__ K, uint4* __restrict__ dst, int nfrag) {
    int tid = blockIdx.x * 256 + threadIdx.x;
    if (tid >= nfrag) return;
    const int lane = tid & 63;
    const int grp  = (tid >> 6) & 1;
    const int ct   = (tid >> 7) & 127;
    const int bh   = tid >> 14;
    const int row  = ct * 16 + (lane & 15);
    const int col  = grp * 32 + (lane >> 4) * 8;
    const float* src = K + ((size_t)bh * S_LEN + row) * DHEAD + col;
    float4 a = *reinterpret_cast<const float4*>(src);
    float4 b = *reinterpret_cast<const float4*>(src + 4);
    uint4 o;
    o.x = pk2h(a.x, a.y); o.y = pk2h(a.z, a.w);
    o.z = pk2h(b.x, b.y); o.w = pk2h(b.z, b.w);
    dst[tid] = o;
}

__global__ __launch_bounds__(256, 4)
void spx_main(const float* __restrict__ Q,
              const unsigned short* __restrict__ Ks,
              const float* __restrict__ V,
              float* __restrict__ O)
{
    // [wave][slot][lane]; wave's 8 KB chunk doubles as fallback p-buffer.
    __shared__ unsigned int s_pack[BWAVES][LCAP][64];   // 32 KB

    const int t    = threadIdx.x;
    const int widx = t >> 6;
    const int l    = t & 63;
    const int lm   = l & 15;
    const int lk   = l >> 4;

    int bid = blockIdx.x;
    if (((int)gridDim.x & 7) == 0)
        bid = (bid & 7) * ((int)gridDim.x >> 3) + (bid >> 3);   // XCD swizzle
    const int nrb   = S_LEN / (WROWS * BWAVES);      // 32 row-blocks per bh
    const int bh    = bid / nrb;
    const int row0w = (bid % nrb) * (WROWS * BWAVES) + widx * WROWS;

    const float* Qf = Q + (size_t)bh * S_LEN * DHEAD;
    const unsigned short* KsB = Ks + (size_t)bh * S_LEN * DHEAD;
    const float* Vb = V + (size_t)bh * S_LEN * DHEAD;
    float* Of = O + (size_t)bh * S_LEN * DHEAD;

    // ---- Q^T B-fragments ----
    f16x8 qfrag[2];
    #pragma unroll
    for (int kp = 0; kp < 2; ++kp) {
        const float* qp = Qf + (size_t)(row0w + lm) * DHEAD + kp * 32 + lk * 8;
        qfrag[kp] = cvt8h(*reinterpret_cast<const float4*>(qp),
                          *reinterpret_cast<const float4*>(qp + 4));
    }

    // transient score tile: S[qrow=lm][ct*16 + lk*4 + e], contiguous frags
    #define SCORE_TILE(a_, ct_)                                                  \
        {                                                                        \
            const unsigned short* kb_ = KsB + (size_t)(ct_) * 1024;              \
            f16x8 k0_ = *reinterpret_cast<const f16x8*>(kb_ + l * 8);            \
            f16x8 k1_ = *reinterpret_cast<const f16x8*>(kb_ + 512 + l * 8);      \
            a_ = (f32x4){0.f, 0.f, 0.f, 0.f};                                    \
            a_ = __builtin_amdgcn_mfma_f32_16x16x32_f16(k0_, qfrag[0], a_, 0, 0, 0); \
            a_ = __builtin_amdgcn_mfma_f32_16x16x32_f16(k1_, qfrag[1], a_, 0, 0, 0); \
        }

    // ---- pass 1: row max ----
    float mx = -FLT_MAX;
    #pragma unroll 8
    for (int ct = 0; ct < S_LEN / 16; ++ct) {
        f32x4 a;
        SCORE_TILE(a, ct);
        mx = fmaxf(mx, fmaxf(fmaxf(a[0], a[1]), fmaxf(a[2], a[3])));
    }
    mx = fmaxf(mx, __shfl_xor(mx, 16));
    mx = fmaxf(mx, __shfl_xor(mx, 32));

    // ---- pass 2: capless (sum,count)@(max-8) -> t1  +  capped collect ----
    int own = 0;
    float startT;
    {
        const float thr0 = mx - 8.f;
        float lsum = 0.f;
        #pragma unroll 2
        for (int ct = 0; ct < S_LEN / 16; ++ct) {
            f32x4 a;
            SCORE_TILE(a, ct);
            #pragma unroll
            for (int e = 0; e < 4; ++e) {
                const float v = a[e];
                if (v > thr0) {
                    lsum += v;
                    if (own < LCAP) {
                        const unsigned int pk =
                            (__builtin_bit_cast(unsigned int, v) & 0xFFFFF800u)
                            | (unsigned int)(ct * 16 + lk * 4 + e);
                        s_pack[widx][own][l] = pk;
                    }
                    ++own;
                }
            }
        }
        for (int i = (own < LCAP ? own : LCAP); i < LCAP; ++i)
            s_pack[widx][i][l] = 0xFF800000u;
        float s2 = lsum, c2 = (float)own;
        s2 += __shfl_xor(s2, 16); c2 += __shfl_xor(c2, 16);
        s2 += __shfl_xor(s2, 32); c2 += __shfl_xor(c2, 32);
        startT = (s2 - 8.f) / c2;        // t1, exact Michelot iterate
    }

    bool ovf = __any(own > LCAP);
    if (ovf) {
        // ---- pass 3 (minority): recollect @ t1, (sum,count)@t1 -> t2 ----
        const float th = startT;
        own = 0;
        float s3 = 0.f, c3 = 0.f;
        #pragma unroll 2
        for (int ct = 0; ct < S_LEN / 16; ++ct) {
            f32x4 a;
            SCORE_TILE(a, ct);
            #pragma unroll
            for (int e = 0; e < 4; ++e) {
                const float v = a[e];
                if (v > th) {
                    s3 += v; c3 += 1.f;
                    if (own < LCAP) {
                        const unsigned int pk =
                            (__builtin_bit_cast(unsigned int, v) & 0xFFFFF800u)
                            | (unsigned int)(ct * 16 + lk * 4 + e);
                        s_pack[widx][own][l] = pk;
                    }
                    ++own;
                }
            }
        }
        for (int i = (own < LCAP ? own : LCAP); i < LCAP; ++i)
            s_pack[widx][i][l] = 0xFF800000u;
        s3 += __shfl_xor(s3, 16); c3 += __shfl_xor(c3, 16);
        s3 += __shfl_xor(s3, 32); c3 += __shfl_xor(c3, 32);
        startT = (s3 - 8.f) / c3;        // t2, exact
        ovf = __any(own > LCAP);
    }

    // wave-wide max slot count (bounds the PV loop)
    int maxc = own < LCAP ? own : LCAP;
    #pragma unroll
    for (int o = 1; o < 64; o <<= 1) {
        const int m2 = __shfl_xor(maxc, o);
        maxc = m2 > maxc ? m2 : maxc;
    }

    float tauF;
    if (!ovf) {
        // ---- in-wave list Michelot from startT (1-2 steps to fixpoint) ----
        float cand[LCAP];
        #pragma unroll
        for (int s = 0; s < LCAP; ++s)
            cand[s] = __builtin_bit_cast(float, s_pack[widx][s][l] & 0xFFFFF800u);
        float tv = startT;
        int cprev = -1;
        for (int it = 0; it < 20; ++it) {
            float s = 0.f, c = 0.f;
            #pragma unroll
            for (int q = 0; q < LCAP; ++q) {
                const bool in = cand[q] > tv;
                s += in ? cand[q] : 0.f;
                c += in ? 1.f : 0.f;
            }
            s += __shfl_xor(s, 16); c += __shfl_xor(c, 16);
            s += __shfl_xor(s, 32); c += __shfl_xor(c, 32);
            tv = (s - 8.f) / c;
            const int C = (int)c;
            const bool done = (C == cprev);
            cprev = C;
            if (__all(done ? 1 : 0)) break;   // fixpoint on all rows: exact
        }
        tauF = tv;

        // ---- branchless interleaved sparse PV (r17/r18-proven) ----
        float tr[WROWS];
        #pragma unroll
        for (int r = 0; r < WROWS; ++r) tr[r] = __shfl(tauF, r);
        float oac[WROWS];
        #pragma unroll
        for (int r = 0; r < WROWS; ++r) oac[r] = 0.f;
        const float* Vl = Vb + l;

        for (int i = 0; i < maxc; ++i) {
            #pragma unroll
            for (int r = 0; r < WROWS; ++r) {
                #pragma unroll
                for (int j = 0; j < 4; ++j) {
                    const unsigned int pk = s_pack[widx][i][r + 16 * j]; // bcast
                    const float val =
                        __builtin_bit_cast(float, pk & 0xFFFFF800u);
                    const float pp = fmaxf(val - tr[r], 0.f);  // 0 for sentinel
                    const int col = (int)(pk & 0x7FFu);
                    oac[r] = fmaf(pp, Vl[(size_t)col * DHEAD], oac[r]);
                }
            }
        }
        #pragma unroll
        for (int r = 0; r < WROWS; ++r)
            Of[(size_t)(row0w + r) * DHEAD + l] = oac[r] * 0.125f;
    } else {
        // ---- fallback: full-scan Michelot from startT + dense PV ----
        float tv = startT;
        int cprev = -1;
        for (int it = 0; it < 12; ++it) {
            float s = 0.f, c = 0.f;
            #pragma unroll 4
            for (int ct = 0; ct < S_LEN / 16; ++ct) {
                f32x4 a;
                SCORE_TILE(a, ct);
                #pragma unroll
                for (int e = 0; e < 4; ++e) {
                    const bool in = a[e] > tv;
                    s += in ? a[e] : 0.f;
                    c += in ? 1.f : 0.f;
                }
            }
            s += __shfl_xor(s, 16); c += __shfl_xor(c, 16);
            s += __shfl_xor(s, 32); c += __shfl_xor(c, 32);
            tv = (s - 8.f) / c;
            const int C = (int)c;
            const bool done = (C == cprev);
            cprev = C;
            if (__all(done ? 1 : 0)) break;
        }
        tauF = tv;

        // dense chunked PV via this wave's own 8 KB LDS chunk as [16][128]
        float* p_lds = reinterpret_cast<float*>(&s_pack[widx][0][0]);
        float ofb[WROWS];
        #pragma unroll
        for (int r = 0; r < WROWS; ++r) ofb[r] = 0.f;
        for (int cc = 0; cc < 16; ++cc) {
            #pragma unroll
            for (int tt = 0; tt < 8; ++tt) {
                f32x4 a;
                SCORE_TILE(a, cc * 8 + tt);
                #pragma unroll
                for (int e = 0; e < 4; ++e)
                    p_lds[lm * 128 + tt * 16 + lk * 4 + e] = fmaxf(a[e] - tauF, 0.f);
            }
            for (int c2 = 0; c2 < 128; ++c2) {
                const float vv = Vb[(size_t)(cc * 128 + c2) * DHEAD + l];
                #pragma unroll
                for (int r = 0; r < WROWS; ++r)
                    ofb[r] += p_lds[r * 128 + c2] * vv;
            }
        }
        #pragma unroll
        for (int r = 0; r < WROWS; ++r)
            Of[(size_t)(row0w + r) * DHEAD + l] = ofb[r] * 0.125f;
    }
    #undef SCORE_TILE
}

extern "C" void kernel_launch(void* const* d_in, const int* in_sizes, int n_in,
                              void* d_out, int out_size, void* d_ws, size_t ws_size,
                              hipStream_t stream) {
    const float* q = (const float*)d_in[0];
    const float* k = (const float*)d_in[1];
    const float* v = (const float*)d_in[2];
    float* out = (float*)d_out;

    const int nElem = in_sizes[0];                    // B*H*S*D = 4194304
    const int BH    = nElem / (S_LEN * DHEAD);

    unsigned short* ks = (unsigned short*)d_ws;
    const int nfrag = nElem / 8;
    kswz_kernel<<<(nfrag + 255) / 256, 256, 0, stream>>>(k, (uint4*)ks, nfrag);

    const int grid = BH * (S_LEN / (WROWS * BWAVES)); // 1024 blocks
    spx_main<<<grid, 256, 0, stream>>>(q, ks, v, out);
}

// Round 21
// 168.354 us; speedup vs baseline: 3.3310x; 1.0759x over previous
//
#include <hip/hip_runtime.h>
#include <float.h>

// Sparsemax attention v13 = r18 EXACTLY + chunked __syncthreads in the three
// (wave-uniform) K-scans, keeping the block's 4 waves within one 16 KB chunk
// so waves 2-4 hit L1 on the shared K-fragment stream (L2 traffic / 4).
// B=2,H=16,S=2048,D=64 fp32, temperature 8.
//
// r20 post-mortem: collecting at max-8 inflated lists 5x (Michelot+PV paid
// it back with interest). Reverted to r18's tight-t1 3-scan structure:
//   pass 1: rowmax.                       [chunk-synced]
//   pass 2: (sum,count)@(max-8) -> t1.    [chunk-synced]
//   pass 3: collect@t1 + (s,c)@t1 -> t2.  [chunk-synced]
//   list Michelot from t2 -> exact tau; branchless interleaved sparse PV.
//   rare overflow -> full-scan Michelot from t2 + dense PV (wave-local,
//   AFTER all barriers -- divergence-safe; correct for any data).

#define S_LEN 2048
#define DHEAD 64
#define WROWS 16
#define BWAVES 4
#define LCAP 32

typedef _Float16 f16x8 __attribute__((ext_vector_type(8)));
typedef __attribute__((ext_vector_type(4))) float f32x4;

__device__ __forceinline__ unsigned short f2h(float x) {
    return __builtin_bit_cast(unsigned short, (_Float16)x);
}
__device__ __forceinline__ unsigned int pk2h(float lo, float hi) {
    return (unsigned int)f2h(lo) | ((unsigned int)f2h(hi) << 16);
}
__device__ __forceinline__ f16x8 cvt8h(float4 a, float4 b) {
    union { unsigned int u[4]; f16x8 v; } r;
    r.u[0] = pk2h(a.x, a.y); r.u[1] = pk2h(a.z, a.w);
    r.u[2] = pk2h(b.x, b.y); r.u[3] = pk2h(b.z, b.w);
    return r.v;
}

// K fp32 [bh][2048][64] -> fragment-contiguous fp16 (r14-proven layout).
__global__ __launch_bounds__(256)
void kswz_kernel(const float* __restrict__ K, uint4* __restrict__ dst, int nfrag) {
    int tid = blockIdx.x * 256 + threadIdx.x;
    if (tid >= nfrag) return;
    const int lane = tid & 63;
    const int grp  = (tid >> 6) & 1;
    const int ct   = (tid >> 7) & 127;
    const int bh   = tid >> 14;
    const int row  = ct * 16 + (lane & 15);
    const int col  = grp * 32 + (lane >> 4) * 8;
    const float* src = K + ((size_t)bh * S_LEN + row) * DHEAD + col;
    float4 a = *reinterpret_cast<const float4*>(src);
    float4 b = *reinterpret_cast<const float4*>(src + 4);
    uint4 o;
    o.x = pk2h(a.x, a.y); o.y = pk2h(a.z, a.w);
    o.z = pk2h(b.x, b.y); o.w = pk2h(b.z, b.w);
    dst[tid] = o;
}

__global__ __launch_bounds__(256, 4)
void spx_main(const float* __restrict__ Q,
              const unsigned short* __restrict__ Ks,
              const float* __restrict__ V,
              float* __restrict__ O)
{
    // [wave][slot][lane]; wave's 8 KB chunk doubles as fallback p-buffer.
    __shared__ unsigned int s_pack[BWAVES][LCAP][64];   // 32 KB

    const int t    = threadIdx.x;
    const int widx = t >> 6;
    const int l    = t & 63;
    const int lm   = l & 15;
    const int lk   = l >> 4;

    int bid = blockIdx.x;
    if (((int)gridDim.x & 7) == 0)
        bid = (bid & 7) * ((int)gridDim.x >> 3) + (bid >> 3);   // XCD swizzle
    const int nrb   = S_LEN / (WROWS * BWAVES);      // 32 row-blocks per bh
    const int bh    = bid / nrb;
    const int row0w = (bid % nrb) * (WROWS * BWAVES) + widx * WROWS;

    const float* Qf = Q + (size_t)bh * S_LEN * DHEAD;
    const unsigned short* KsB = Ks + (size_t)bh * S_LEN * DHEAD;
    const float* Vb = V + (size_t)bh * S_LEN * DHEAD;
    float* Of = O + (size_t)bh * S_LEN * DHEAD;

    // ---- Q^T B-fragments ----
    f16x8 qfrag[2];
    #pragma unroll
    for (int kp = 0; kp < 2; ++kp) {
        const float* qp = Qf + (size_t)(row0w + lm) * DHEAD + kp * 32 + lk * 8;
        qfrag[kp] = cvt8h(*reinterpret_cast<const float4*>(qp),
                          *reinterpret_cast<const float4*>(qp + 4));
    }

    // transient score tile: S[qrow=lm][ct*16 + lk*4 + e], contiguous frags
    #define SCORE_TILE(a_, ct_)                                                  \
        {                                                                        \
            const unsigned short* kb_ = KsB + (size_t)(ct_) * 1024;              \
            f16x8 k0_ = *reinterpret_cast<const f16x8*>(kb_ + l * 8);            \
            f16x8 k1_ = *reinterpret_cast<const f16x8*>(kb_ + 512 + l * 8);      \
            a_ = (f32x4){0.f, 0.f, 0.f, 0.f};                                    \
            a_ = __builtin_amdgcn_mfma_f32_16x16x32_f16(k0_, qfrag[0], a_, 0, 0, 0); \
            a_ = __builtin_amdgcn_mfma_f32_16x16x32_f16(k1_, qfrag[1], a_, 0, 0, 0); \
        }

    // ---- pass 1: row max (chunk-synced: 8 tiles = 16 KB < L1) ----
    float mx = -FLT_MAX;
    for (int cc = 0; cc < 16; ++cc) {
        #pragma unroll
        for (int tt = 0; tt < 8; ++tt) {
            f32x4 a;
            SCORE_TILE(a, cc * 8 + tt);
            mx = fmaxf(mx, fmaxf(fmaxf(a[0], a[1]), fmaxf(a[2], a[3])));
        }
        __syncthreads();
    }
    mx = fmaxf(mx, __shfl_xor(mx, 16));
    mx = fmaxf(mx, __shfl_xor(mx, 32));

    // ---- pass 2: (sum,count)@(max-8) -> t1 (chunk-synced) ----
    float t1;
    {
        const float thr0 = mx - 8.f;
        float s2 = 0.f, c2 = 0.f;
        for (int cc = 0; cc < 16; ++cc) {
            #pragma unroll
            for (int tt = 0; tt < 8; ++tt) {
                f32x4 a;
                SCORE_TILE(a, cc * 8 + tt);
                #pragma unroll
                for (int e = 0; e < 4; ++e) {
                    const bool in = a[e] > thr0;
                    s2 += in ? a[e] : 0.f;
                    c2 += in ? 1.f : 0.f;
                }
            }
            __syncthreads();
        }
        s2 += __shfl_xor(s2, 16); c2 += __shfl_xor(c2, 16);
        s2 += __shfl_xor(s2, 32); c2 += __shfl_xor(c2, 32);
        t1 = (s2 - 8.f) / c2;            // c2 >= 1 (max itself qualifies)
    }

    // ---- pass 3: collect {s > t1} + (sum,count)@t1 -> t2 (chunk-synced) ----
    int own = 0;
    float t2;
    {
        float s3 = 0.f, c3 = 0.f;
        for (int cc = 0; cc < 16; ++cc) {
            #pragma unroll
            for (int tt = 0; tt < 8; ++tt) {
                f32x4 a;
                SCORE_TILE(a, cc * 8 + tt);
                #pragma unroll
                for (int e = 0; e < 4; ++e) {
                    const float v = a[e];
                    if (v > t1) {
                        s3 += v; c3 += 1.f;
                        if (own < LCAP) {
                            const unsigned int pk =
                                (__builtin_bit_cast(unsigned int, v) & 0xFFFFF800u)
                                | (unsigned int)((cc * 8 + tt) * 16 + lk * 4 + e);
                            s_pack[widx][own][l] = pk;
                        }
                        ++own;
                    }
                }
            }
            __syncthreads();
        }
        // sentinel-pad (-inf packed, col 0)
        for (int i = (own < LCAP ? own : LCAP); i < LCAP; ++i)
            s_pack[widx][i][l] = 0xFF800000u;
        s3 += __shfl_xor(s3, 16); c3 += __shfl_xor(c3, 16);
        s3 += __shfl_xor(s3, 32); c3 += __shfl_xor(c3, 32);
        t2 = (s3 - 8.f) / c3;            // c3 >= 1 (max > t1 always)
    }

    // wave-wide max slot count (bounds the PV loop)
    int maxc = own < LCAP ? own : LCAP;
    #pragma unroll
    for (int o = 1; o < 64; o <<= 1) {
        const int m2 = __shfl_xor(maxc, o);
        maxc = m2 > maxc ? m2 : maxc;
    }

    const bool ovf = __any(own > LCAP);
    float tauF;
    if (!ovf) {
        // ---- in-wave list Michelot from t2 (1-2 steps to fixpoint) ----
        float cand[LCAP];
        #pragma unroll
        for (int s = 0; s < LCAP; ++s)
            cand[s] = __builtin_bit_cast(float, s_pack[widx][s][l] & 0xFFFFF800u);
        float tv = t2;
        int cprev = -1;
        for (int it = 0; it < 20; ++it) {
            float s = 0.f, c = 0.f;
            #pragma unroll
            for (int q = 0; q < LCAP; ++q) {
                const bool in = cand[q] > tv;
                s += in ? cand[q] : 0.f;
                c += in ? 1.f : 0.f;
            }
            s += __shfl_xor(s, 16); c += __shfl_xor(c, 16);
            s += __shfl_xor(s, 32); c += __shfl_xor(c, 32);
            tv = (s - 8.f) / c;
            const int C = (int)c;
            const bool done = (C == cprev);
            cprev = C;
            if (__all(done ? 1 : 0)) break;   // fixpoint on all rows: exact
        }
        tauF = tv;

        // ---- branchless interleaved sparse PV (r17/r18-proven) ----
        float tr[WROWS];
        #pragma unroll
        for (int r = 0; r < WROWS; ++r) tr[r] = __shfl(tauF, r);
        float oac[WROWS];
        #pragma unroll
        for (int r = 0; r < WROWS; ++r) oac[r] = 0.f;
        const float* Vl = Vb + l;

        for (int i = 0; i < maxc; ++i) {
            #pragma unroll
            for (int r = 0; r < WROWS; ++r) {
                #pragma unroll
                for (int j = 0; j < 4; ++j) {
                    const unsigned int pk = s_pack[widx][i][r + 16 * j]; // bcast
                    const float val =
                        __builtin_bit_cast(float, pk & 0xFFFFF800u);
                    const float pp = fmaxf(val - tr[r], 0.f);  // 0 for sentinel
                    const int col = (int)(pk & 0x7FFu);
                    oac[r] = fmaf(pp, Vl[(size_t)col * DHEAD], oac[r]);
                }
            }
        }
        #pragma unroll
        for (int r = 0; r < WROWS; ++r)
            Of[(size_t)(row0w + r) * DHEAD + l] = oac[r] * 0.125f;
    } else {
        // ---- fallback: full-scan Michelot from t2 (cheap) + dense PV ----
        float tv = t2;
        int cprev = -1;
        for (int it = 0; it < 12; ++it) {
            float s = 0.f, c = 0.f;
            #pragma unroll 4
            for (int ct = 0; ct < S_LEN / 16; ++ct) {
                f32x4 a;
                SCORE_TILE(a, ct);
                #pragma unroll
                for (int e = 0; e < 4; ++e) {
                    const bool in = a[e] > tv;
                    s += in ? a[e] : 0.f;
                    c += in ? 1.f : 0.f;
                }
            }
            s += __shfl_xor(s, 16); c += __shfl_xor(c, 16);
            s += __shfl_xor(s, 32); c += __shfl_xor(c, 32);
            tv = (s - 8.f) / c;
            const int C = (int)c;
            const bool done = (C == cprev);
            cprev = C;
            if (__all(done ? 1 : 0)) break;
        }
        tauF = tv;

        // dense chunked PV via this wave's own 8 KB LDS chunk as [16][128]
        float* p_lds = reinterpret_cast<float*>(&s_pack[widx][0][0]);
        float ofb[WROWS];
        #pragma unroll
        for (int r = 0; r < WROWS; ++r) ofb[r] = 0.f;
        for (int cc = 0; cc < 16; ++cc) {
            #pragma unroll
            for (int tt = 0; tt < 8; ++tt) {
                f32x4 a;
                SCORE_TILE(a, cc * 8 + tt);
                #pragma unroll
                for (int e = 0; e < 4; ++e)
                    p_lds[lm * 128 + tt * 16 + lk * 4 + e] = fmaxf(a[e] - tauF, 0.f);
            }
            for (int c2 = 0; c2 < 128; ++c2) {
                const float vv = Vb[(size_t)(cc * 128 + c2) * DHEAD + l];
                #pragma unroll
                for (int r = 0; r < WROWS; ++r)
                    ofb[r] += p_lds[r * 128 + c2] * vv;
            }
        }
        #pragma unroll
        for (int r = 0; r < WROWS; ++r)
            Of[(size_t)(row0w + r) * DHEAD + l] = ofb[r] * 0.125f;
    }
    #undef SCORE_TILE
}

extern "C" void kernel_launch(void* const* d_in, const int* in_sizes, int n_in,
                              void* d_out, int out_size, void* d_ws, size_t ws_size,
                              hipStream_t stream) {
    const float* q = (const float*)d_in[0];
    const float* k = (const float*)d_in[1];
    const float* v = (const float*)d_in[2];
    float* out = (float*)d_out;

    const int nElem = in_sizes[0];                    // B*H*S*D = 4194304
    const int BH    = nElem / (S_LEN * DHEAD);

    unsigned short* ks = (unsigned short*)d_ws;
    const int nfrag = nElem / 8;
    kswz_kernel<<<(nfrag + 255) / 256, 256, 0, stream>>>(k, (uint4*)ks, nfrag);

    const int grid = BH * (S_LEN / (WROWS * BWAVES)); // 1024 blocks
    spx_main<<<grid, 256, 0, stream>>>(q, ks, v, out);
}